// Round 12
// baseline (436.836 us; speedup 1.0000x reference)
//
#include <hip/hip_runtime.h>
#include <hip/hip_bf16.h>

#define C_   128
#define A_   4
#define S_   16
#define RH_  64
#define H_   8
#define AH_  256
#define OUT_ 128

typedef __attribute__((ext_vector_type(8))) short bf16x8;
typedef __attribute__((ext_vector_type(4))) float f32x4;

__device__ __forceinline__ float sigf(float x) { return 1.0f / (1.0f + __expf(-x)); }

__device__ __forceinline__ unsigned short f2bf(float x) {
    unsigned u = __float_as_uint(x);
    unsigned r = (u + 0x7fffu + ((u >> 16) & 1u)) >> 16;   // RNE
    return (unsigned short)r;
}
__device__ __forceinline__ float bf2f(unsigned short v) {
    return __uint_as_float((unsigned)v << 16);
}

// packed pair f32->bf16 (compiler emits v_cvt_pk_bf16_f32)
__device__ __forceinline__ unsigned pkbf(float a, float b) {
    union { __hip_bfloat162 h; unsigned u; } c;
    c.h = __float22bfloat162_rn(float2{a, b});
    return c.u;
}

// monotone float <-> uint mapping for atomicMax-based segment max
__device__ __forceinline__ unsigned enc(float x) {
    unsigned b = __float_as_uint(x);
    return (b & 0x80000000u) ? ~b : (b | 0x80000000u);
}
__device__ __forceinline__ float dec(unsigned u) {
    unsigned b = (u & 0x80000000u) ? (u & 0x7fffffffu) : ~u;
    return __uint_as_float(b);
}

// Pack f32 weight W[K][N] into bf16 fragment-linear layout for mfma_f32_16x16x32_bf16:
// out[((ct*(K/32)+ks)*64 + l)*8 + j] = W[ks*32 + (l>>4)*8 + j][ct*16 + (l&15)]
__global__ void k_pack(const float* __restrict__ W, short* __restrict__ out, int K, int N) {
    const int KS = K / 32;
    const int ct = blockIdx.x / KS, ks = blockIdx.x % KS;
    const int l = threadIdx.x, lr = l & 15, lg = l >> 4;
    bf16x8 v;
    #pragma unroll
    for (int j = 0; j < 8; j++)
        v[j] = (short)f2bf(W[(size_t)(ks * 32 + lg * 8 + j) * N + ct * 16 + lr]);
    *(bf16x8*)&out[((size_t)blockIdx.x * 64 + l) * 8] = v;
}

// Pack w_rad2 [64][512] as B'[k][c] with k = r*4+a (K=256), c in [0,128)
__global__ void k_pack_dtp(const float* __restrict__ W, short* __restrict__ out) {
    const int ct = blockIdx.x >> 3, ks = blockIdx.x & 7;
    const int l = threadIdx.x, lr = l & 15, lg = l >> 4;
    bf16x8 v;
    #pragma unroll
    for (int j = 0; j < 8; j++)
        v[j] = (short)f2bf(W[(size_t)(ks * 8 + lg * 2 + (j >> 2)) * 512 + (ct * 16 + lr) * 4 + (j & 3)]);
    *(bf16x8*)&out[((size_t)blockIdx.x * 64 + l) * 8] = v;
}

// CSR build: histogram, scan, fill (sorted edge list)
__global__ __launch_bounds__(256) void k_hist(
    const int* __restrict__ edge_dst, int* __restrict__ deg, int E)
{
    const int e = blockIdx.x * 256 + threadIdx.x;
    if (e < E) atomicAdd(&deg[edge_dst[e]], 1);
}

__global__ __launch_bounds__(1024) void k_scan(
    const int* __restrict__ deg, int* __restrict__ cursor, int N)
{
    __shared__ int part[1024];
    const int t = threadIdx.x;
    const int per = (N + 1023) / 1024;
    const int i0 = t * per;
    int s = 0;
    for (int i = 0; i < per; i++) { int idx = i0 + i; if (idx < N) s += deg[idx]; }
    part[t] = s;
    __syncthreads();
    for (int off = 1; off < 1024; off <<= 1) {
        int v = (t >= off) ? part[t - off] : 0;
        __syncthreads();
        part[t] += v;
        __syncthreads();
    }
    int excl = (t == 0) ? 0 : part[t - 1];
    for (int i = 0; i < per; i++) {
        int idx = i0 + i;
        if (idx < N) { cursor[idx] = excl; excl += deg[idx]; }
    }
}

__global__ __launch_bounds__(256) void k_fill(
    const int* __restrict__ edge_dst, int* __restrict__ cursor,
    int* __restrict__ sorted, int E)
{
    const int e = blockIdx.x * 256 + threadIdx.x;
    if (e < E) {
        const int pos = atomicAdd(&cursor[edge_dst[e]], 1);
        sorted[pos] = e;
    }
}

// Fused msg + alpha. 32 edges/block, 256 threads (4 waves), ~24.6KB LDS.
// (256,5): fragments are K-chunked (live set 32 regs, was 64) so total
// VGPR+AGPR fits 5 waves/SIMD without spill. (256,6) spilled (R7);
// un-chunked fragments capped occupancy at ~4 waves/SIMD (R8-R11, 42%).
__global__ __launch_bounds__(256, 5) void k_msgalpha(
    const float* __restrict__ message, const float* __restrict__ edge_attr,
    const float* __restrict__ edge_scalars,
    const float* __restrict__ w_rad1, const float* __restrict__ b_rad1,
    const short* __restrict__ w_rad2_lin, const float* __restrict__ b_rad2,
    const short* __restrict__ w_alpha_lin, const float* __restrict__ b_alpha,
    const float* __restrict__ alpha_dot, const int* __restrict__ edge_dst,
    short* __restrict__ msg_bf, float* __restrict__ logits, unsigned* __restrict__ amax_u)
{
    __shared__ __align__(16) char smem[25216];
    short* Ap     = (short*)smem;                     // [32] rows x 512B, swz (r&31)<<4
    short* msg_s  = (short*)(smem + 16384);           // [32] rows x 256B, swz (r&15)<<4
    float* w1_s   = (float*)(smem + 16384);           // overlay [16][64]
    float* es_s   = (float*)(smem + 16384 + 4096);    // overlay [32][17]
    float* attr_s = (float*)(smem + 24576);           // [32][4]
    int*   dst_s  = (int*)(smem + 25088);             // [32]

    const int t = threadIdx.x;
    const long e0 = (long)blockIdx.x * 32;

    *(float4*)&w1_s[t * 4] = *(const float4*)&w_rad1[t * 4];
    if (t < 128) {
        const int r = t >> 2, s4 = (t & 3) * 4;
        *(float4*)&es_s[r * 17 + s4] = *(const float4*)&edge_scalars[(e0 + r) * S_ + s4];
    }
    if (t < 32) {
        *(float4*)&attr_s[t * 4] = *(const float4*)&edge_attr[(e0 + t) * A_];
        dst_s[t] = edge_dst[e0 + t];
    }
    __syncthreads();

    {   // Phase A: h = silu(es @ w_rad1 + b1); A'[r, 4c+a] = h[r,c]*attr[r,a]
        const int r = t & 31, o0 = (t >> 5) * 8;
        float acc[8];
        #pragma unroll
        for (int i = 0; i < 8; i++) acc[i] = b_rad1[o0 + i];
        #pragma unroll
        for (int s = 0; s < S_; s++) {
            const float ev = es_s[r * 17 + s];
            #pragma unroll
            for (int i = 0; i < 8; i++) acc[i] += ev * w1_s[s * 64 + o0 + i];
        }
        float h[8];
        #pragma unroll
        for (int i = 0; i < 8; i++) { const float x = acc[i]; h[i] = x * sigf(x); }
        const float4 a4 = *(const float4*)&attr_s[r * 4];
        char* base = (char*)Ap + r * 512;
        const int sw = (r & 31) << 4;
        #pragma unroll
        for (int c = 0; c < 4; c++) {
            const float h0 = h[2 * c], h1 = h[2 * c + 1];
            uint4 v;
            v.x = pkbf(h0 * a4.x, h0 * a4.y);
            v.y = pkbf(h0 * a4.z, h0 * a4.w);
            v.z = pkbf(h1 * a4.x, h1 * a4.y);
            v.w = pkbf(h1 * a4.z, h1 * a4.w);
            *(uint4*)(base + ((o0 * 8 + c * 16) ^ sw)) = v;
        }
    }
    __syncthreads();

    const int w = t >> 6, l = t & 63, lr = l & 15, lg = l >> 4;

    {   // Phase B: tp = A'(32x256) @ B'(256x128); msg = message * tp -> msg_s
        // K-chunked: bf[4]+af[4] live (32 regs), weights reload per rt (L2-hot)
        #pragma unroll
        for (int q = 0; q < 2; q++) {
            const int ct = w * 2 + q;
            const int col = ct * 16 + lr;
            const float4 b2 = *(const float4*)&b_rad2[col * 4];
            #pragma unroll
            for (int rt = 0; rt < 2; rt++) {
                const int arow = rt * 16 + lr;
                const char* abase = (char*)Ap + arow * 512;
                const int asw = (arow & 31) << 4;
                f32x4 acc = {0.f, 0.f, 0.f, 0.f};
                #pragma unroll
                for (int kc = 0; kc < 2; kc++) {
                    bf16x8 bf[4], af[4];
                    #pragma unroll
                    for (int ks = 0; ks < 4; ks++) {
                        bf[ks] = *(const bf16x8*)&w_rad2_lin[((size_t)(ct * 8 + kc * 4 + ks) * 64 + l) * 8];
                        af[ks] = *(const bf16x8*)(abase + (((kc * 4 + ks) * 64 + lg * 16) ^ asw));
                    }
                    #pragma unroll
                    for (int ks = 0; ks < 4; ks++)
                        acc = __builtin_amdgcn_mfma_f32_16x16x32_bf16(af[ks], bf[ks], acc, 0, 0, 0);
                }
                #pragma unroll
                for (int r = 0; r < 4; r++) {
                    const int row = rt * 16 + lg * 4 + r;
                    const float4 a4 = *(const float4*)&attr_s[row * 4];
                    const float badj = a4.x * b2.x + a4.y * b2.y + a4.z * b2.z + a4.w * b2.w;
                    const float m = message[(e0 + row) * C_ + col];
                    *(short*)((char*)msg_s + row * 256 + ((col * 2) ^ ((row & 15) << 4))) =
                        (short)f2bf(m * (acc[r] + badj));
                }
            }
        }
    }
    __syncthreads();

    {   // Phase C: msg_s -> global (linear bf16 rows)
        #pragma unroll
        for (int i = 0; i < 2; i++) {
            const int q = t + i * 256;
            const int row = q >> 4, ch = q & 15;
            const uint4 v = *(const uint4*)((char*)msg_s + row * 256 + ((ch * 16) ^ ((row & 15) << 4)));
            *(uint4*)((char*)msg_bf + ((e0 + row) * 256 + ch * 16)) = v;
        }
    }

    {   // Phase D: transposed alpha GEMM; wave w owns heads {2w, 2w+1}.
        // waf[4] + single mb live (24 regs); mb reloaded from LDS per (q,ct).
        #pragma unroll
        for (int hq = 0; hq < 2; hq++) {
            const int hd = w * 2 + hq;
            float s0 = 0.f, s1 = 0.f;
            #pragma unroll
            for (int q = 0; q < 2; q++) {
                const int ctw = hd * 2 + q;
                bf16x8 waf[4];
                #pragma unroll
                for (int ks = 0; ks < 4; ks++)
                    waf[ks] = *(const bf16x8*)&w_alpha_lin[((size_t)(ctw * 4 + ks) * 64 + l) * 8];
                const float4 ba4 = *(const float4*)&b_alpha[ctw * 16 + lg * 4];
                const float4 ad4 = *(const float4*)&alpha_dot[ctw * 16 + lg * 4];
                #pragma unroll
                for (int ct = 0; ct < 2; ct++) {
                    const int erow = ct * 16 + lr;
                    const char* mbase = (char*)msg_s + erow * 256;
                    const int msw = (erow & 15) << 4;
                    f32x4 acc = {0.f, 0.f, 0.f, 0.f};
                    #pragma unroll
                    for (int ks = 0; ks < 4; ks++) {
                        const bf16x8 mb = *(const bf16x8*)(mbase + ((ks * 64 + lg * 16) ^ msw));
                        acc = __builtin_amdgcn_mfma_f32_16x16x32_bf16(waf[ks], mb, acc, 0, 0, 0);
                    }
                    float sl = 0.f;
                    #pragma unroll
                    for (int r = 0; r < 4; r++) {
                        const float x = acc[r] + ((const float*)&ba4)[r];
                        const float y = x * (0.2f + 0.8f * sigf(x));   // SmoothLeakyReLU a=0.2
                        sl += y * ((const float*)&ad4)[r];
                    }
                    if (ct == 0) s0 += sl; else s1 += sl;
                }
            }
            #pragma unroll
            for (int ct = 0; ct < 2; ct++) {
                float v = (ct == 0) ? s0 : s1;
                v += __shfl_xor(v, 16);
                v += __shfl_xor(v, 32);
                if (lg == 0) {
                    const long e = e0 + ct * 16 + lr;
                    logits[e * H_ + hd] = v;
                    atomicMax(&amax_u[dst_s[ct * 16 + lr] * H_ + hd], enc(v));
                }
            }
        }
    }
}

// K3: denom via run-length over 8 sorted edges per thread (1 head each).
// Atomics drop ~8x vs per-(edge,head); reads gather but 8 lanes share rows.
__global__ __launch_bounds__(256) void k_denom(
    const float* __restrict__ logits, const int* __restrict__ edge_dst,
    const int* __restrict__ sorted, const unsigned* __restrict__ amax_u,
    float* __restrict__ denom, int E)
{
    const int idx = blockIdx.x * 256 + threadIdx.x;
    if (idx >= E) return;
    const int g = idx >> 3, h = idx & 7;
    int nprev = -1; float run = 0.f, am = 0.f;
    #pragma unroll 1
    for (int e = 0; e < 8; e++) {
        const int eid = sorted[g * 8 + e];
        const int n = edge_dst[eid];
        if (n != nprev) {
            if (nprev >= 0) atomicAdd(&denom[nprev * H_ + h], run);
            nprev = n; run = 0.f;
            am = dec(amax_u[n * H_ + h]);
        }
        run += __expf(logits[(size_t)eid * H_ + h] - am);
    }
    atomicAdd(&denom[nprev * H_ + h], run);
}

// K4: dst-sorted edges, 32 per block, 256 threads (4 waves), ~19KB LDS.
// val2 bf16 [32][264] overlays staging -> ~5 blocks/CU. Gate GEMM: each wave
// owns col-tiles {2w, 2w+1}.
__global__ __launch_bounds__(256, 5) void k_value(
    const short* __restrict__ msg_bf, const float* __restrict__ edge_attr,
    const short* __restrict__ w_lin_act_lin, const float* __restrict__ b_lin_act,
    const float* __restrict__ w_dtp_v,
    const short* __restrict__ w_lin_v_lin, const float* __restrict__ b_lin_v,
    const float* __restrict__ logits, const int* __restrict__ edge_dst,
    const unsigned* __restrict__ amax_u, const float* __restrict__ denom,
    const int* __restrict__ sorted, float* __restrict__ node)
{
    __shared__ __align__(16) char pool[16896];   // max(a_s 8K + v_s 8K, val2 32x264 bf16)
    __shared__ float attr_s[32][4];
    __shared__ float wgt_s[32][H_];
    __shared__ int   dst_s[32];
    __shared__ int   eid_s[32];
    short* a_s  = (short*)pool;            // [32] rows x 256B, swizzle (row&15)<<4
    short* v_s  = (short*)(pool + 8192);   // [32] rows x 256B, swizzle (row&15)<<4
    short* val2 = (short*)pool;            // [32][264] bf16 overlay

    const int t = threadIdx.x;
    const int b0 = blockIdx.x * 32;

    if (t < 32) {
        const int e = sorted[b0 + t];
        eid_s[t] = e;
        dst_s[t] = edge_dst[e];
        *(float4*)&attr_s[t][0] = *(const float4*)&edge_attr[(long)e * A_];
    }
    __syncthreads();
    #pragma unroll
    for (int i = 0; i < 2; i++) {   // gather msg rows -> swizzled LDS
        const int q = t + i * 256;
        const int row = q >> 4, ch = q & 15;
        const uint4 v = *(const uint4*)((const char*)msg_bf + ((long)eid_s[row] * 256 + ch * 16));
        *(uint4*)((char*)a_s + row * 256 + ((ch * 16) ^ ((row & 15) << 4))) = v;
    }
    {   // softmax weights, one (el,h) per thread
        const int el = t >> 3, h = t & 7;
        const long e = eid_s[el];
        const int n = dst_s[el];
        const float am = dec(amax_u[n * H_ + h]);
        const float d  = denom[n * H_ + h];
        wgt_s[el][h] = __expf(logits[e * H_ + h] - am) / (d + 1e-16f);
    }
    __syncthreads();

    const int w = t >> 6, l = t & 63, lr = l & 15, lg = l >> 4;
    {   // gate GEMM: wave w owns col-tiles {2w, 2w+1} (32 of 128 cols), 32 rows
        bf16x8 af[2][4];
        #pragma unroll
        for (int rt = 0; rt < 2; rt++)
            #pragma unroll
            for (int ks = 0; ks < 4; ks++) {
                const int arow = rt * 16 + lr;
                af[rt][ks] = *(bf16x8*)((char*)a_s + arow * 256 + ((ks * 64 + lg * 16) ^ ((arow & 15) << 4)));
            }
        #pragma unroll
        for (int q = 0; q < 2; q++) {
            const int ct = w * 2 + q;
            bf16x8 bfg[4];
            #pragma unroll
            for (int ks = 0; ks < 4; ks++)
                bfg[ks] = *(const bf16x8*)&w_lin_act_lin[((size_t)(ct * 4 + ks) * 64 + l) * 8];
            const int col = ct * 16 + lr;
            const float bb = b_lin_act[col];
            const float4 wv = *(const float4*)&w_dtp_v[col * 4];
            #pragma unroll
            for (int rt = 0; rt < 2; rt++) {
                f32x4 acc = {0.f, 0.f, 0.f, 0.f};
                #pragma unroll
                for (int ks = 0; ks < 4; ks++)
                    acc = __builtin_amdgcn_mfma_f32_16x16x32_bf16(af[rt][ks], bfg[ks], acc, 0, 0, 0);
                #pragma unroll
                for (int r = 0; r < 4; r++) {
                    const int row = rt * 16 + lg * 4 + r;
                    float x = acc[r] + bb;
                    x = x * sigf(x);
                    const float4 a4 = *(const float4*)&attr_s[row][0];
                    const float dv = wv.x * a4.x + wv.y * a4.y + wv.z * a4.z + wv.w * a4.w;
                    *(short*)((char*)v_s + row * 256 + ((col * 2) ^ ((row & 15) << 4))) =
                        (short)f2bf(x * dv);
                }
            }
        }
    }
    __syncthreads();

    bf16x8 vf[2][4];
    #pragma unroll
    for (int rt = 0; rt < 2; rt++)
        #pragma unroll
        for (int ks = 0; ks < 4; ks++) {
            const int row = rt * 16 + lr;
            vf[rt][ks] = *(bf16x8*)((char*)v_s + row * 256 + ((ks * 64 + lg * 16) ^ ((row & 15) << 4)));
        }
    __syncthreads();   // all v_s reads done; pool reusable as val2

    #pragma unroll
    for (int q = 0; q < 4; q++) {   // value GEMM: wave w owns col-tiles w*4..w*4+3
        const int ct = w * 4 + q;
        bf16x8 bf[4];
        #pragma unroll
        for (int ks = 0; ks < 4; ks++)
            bf[ks] = *(const bf16x8*)&w_lin_v_lin[((size_t)(ct * 4 + ks) * 64 + l) * 8];
        const int col = ct * 16 + lr;
        const float bb = b_lin_v[col];
        #pragma unroll
        for (int rt = 0; rt < 2; rt++) {
            f32x4 acc = {0.f, 0.f, 0.f, 0.f};
            #pragma unroll
            for (int ks = 0; ks < 4; ks++)
                acc = __builtin_amdgcn_mfma_f32_16x16x32_bf16(vf[rt][ks], bf[ks], acc, 0, 0, 0);
            #pragma unroll
            for (int r = 0; r < 4; r++) {
                const int row = rt * 16 + lg * 4 + r;
                val2[row * 264 + col] = (short)f2bf((acc[r] + bb) * wgt_s[row][col >> 5]);
            }
        }
    }
    __syncthreads();
    {   // run-length reduce by dst; thread owns channel t over all 32 edges
        const int c = t;
        float run = 0.f;
        int s = 0;
        #pragma unroll 1
        for (int e = 0; e < 32; e++) {
            run += bf2f((unsigned short)val2[e * 264 + c]);
            const bool end = (e == 31) || (dst_s[e + 1] != dst_s[e]);
            if (end) {
                float* np = node + (long)dst_s[e] * AH_ + c;
                if (s == 0 || e == 31) atomicAdd(np, run);
                else *np = run;
                run = 0.f; s = e + 1;
            }
        }
    }
}

// K5: out = node @ w_proj + b_proj
__global__ __launch_bounds__(256) void k_proj(
    const float* __restrict__ node, const float* __restrict__ w_proj,
    const float* __restrict__ b_proj, float* __restrict__ out)
{
    __shared__ float node_s[32][AH_];
    const int t = threadIdx.x;
    const long n0 = (long)blockIdx.x * 32;
    #pragma unroll
    for (int i = 0; i < 8; i++) {
        const int idx = t + i * 256;
        const int nl = idx >> 6, c4 = (idx & 63) * 4;
        *(float4*)&node_s[nl][c4] = *(const float4*)&node[(n0 + nl) * AH_ + c4];
    }
    __syncthreads();
    const int j0 = (t & 31) * 4;
    const int g  = t >> 5;
    float4 acc4[4];
    const float4 b = *(const float4*)&b_proj[j0];
    #pragma unroll
    for (int i = 0; i < 4; i++) acc4[i] = b;
    const float* wp = w_proj + j0;
    for (int c4 = 0; c4 < 64; c4++) {
        const float4 w0 = *(const float4*)&wp[(c4 * 4 + 0) * OUT_];
        const float4 w1 = *(const float4*)&wp[(c4 * 4 + 1) * OUT_];
        const float4 w2 = *(const float4*)&wp[(c4 * 4 + 2) * OUT_];
        const float4 w3 = *(const float4*)&wp[(c4 * 4 + 3) * OUT_];
        #pragma unroll
        for (int i = 0; i < 4; i++) {
            const float4 nv = *(const float4*)&node_s[g * 4 + i][c4 * 4];
            acc4[i].x += nv.x * w0.x + nv.y * w1.x + nv.z * w2.x + nv.w * w3.x;
            acc4[i].y += nv.x * w0.y + nv.y * w1.y + nv.z * w2.y + nv.w * w3.y;
            acc4[i].z += nv.x * w0.z + nv.y * w1.z + nv.z * w2.z + nv.w * w3.z;
            acc4[i].w += nv.x * w0.w + nv.y * w1.w + nv.z * w2.w + nv.w * w3.w;
        }
    }
    #pragma unroll
    for (int i = 0; i < 4; i++) {
        const long n = n0 + g * 4 + i;
        *(float4*)&out[n * OUT_ + j0] = acc4[i];
    }
}

extern "C" void kernel_launch(void* const* d_in, const int* in_sizes, int n_in,
                              void* d_out, int out_size, void* d_ws, size_t ws_size,
                              hipStream_t stream)
{
    const float* message      = (const float*)d_in[0];
    const float* edge_attr    = (const float*)d_in[1];
    const float* edge_scalars = (const float*)d_in[2];
    const float* w_rad1       = (const float*)d_in[3];
    const float* b_rad1       = (const float*)d_in[4];
    const float* w_rad2       = (const float*)d_in[5];
    const float* b_rad2       = (const float*)d_in[6];
    const float* w_dtp_v      = (const float*)d_in[7];
    const float* w_lin_act    = (const float*)d_in[8];
    const float* b_lin_act    = (const float*)d_in[9];
    const float* w_alpha      = (const float*)d_in[10];
    const float* b_alpha      = (const float*)d_in[11];
    const float* w_lin_v      = (const float*)d_in[12];
    const float* b_lin_v      = (const float*)d_in[13];
    const float* alpha_dot    = (const float*)d_in[14];
    const float* w_proj       = (const float*)d_in[15];
    const float* b_proj       = (const float*)d_in[16];
    const int*   edge_dst     = (const int*)d_in[17];

    const int E = in_sizes[0] / C_;
    const int N = out_size / OUT_;

    // ws layout (zeroed region first):
    // [node N*256 f32][amax N*8 u32][denom N*8 f32][deg N i32] |
    // [cursor N][sorted E][wpacks][msg_bf E*128 s][logits E*8 f32]
    char* ws = (char*)d_ws;
    float*    node     = (float*)ws;
    unsigned* amax_u   = (unsigned*)(node + (size_t)N * AH_);
    float*    denom    = (float*)(amax_u + (size_t)N * H_);
    int*      deg      = (int*)(denom + (size_t)N * H_);
    int*      cursor   = deg + N;
    int*      sorted   = cursor + N;
    short*    w_rad2_l = (short*)(sorted + E);
    short*    w_alph_l = w_rad2_l + 64 * 512;
    short*    w_lact_l = w_alph_l + 128 * 256;
    short*    w_linv_l = w_lact_l + 128 * 128;
    short*    msg_bf   = w_linv_l + 128 * 256;
    float*    logits   = (float*)(msg_bf + (size_t)E * C_);

    hipMemsetAsync(d_ws, 0, (size_t)N * (AH_ + 2 * H_ + 1) * 4, stream);

    const int nbE256 = (E + 255) / 256;
    k_pack_dtp<<<64, 64, 0, stream>>>(w_rad2, w_rad2_l);
    k_pack<<<(256/16)*(128/32), 64, 0, stream>>>(w_alpha,   w_alph_l, 128, 256);
    k_pack<<<(128/16)*(128/32), 64, 0, stream>>>(w_lin_act, w_lact_l, 128, 128);
    k_pack<<<(256/16)*(128/32), 64, 0, stream>>>(w_lin_v,   w_linv_l, 128, 256);
    k_hist<<<nbE256, 256, 0, stream>>>(edge_dst, deg, E);
    k_scan<<<1, 1024, 0, stream>>>(deg, cursor, N);
    k_fill<<<nbE256, 256, 0, stream>>>(edge_dst, cursor, sorted, E);
    k_msgalpha<<<E / 32, 256, 0, stream>>>(message, edge_attr, edge_scalars,
                                           w_rad1, b_rad1, w_rad2_l, b_rad2,
                                           w_alph_l, b_alpha, alpha_dot, edge_dst,
                                           msg_bf, logits, amax_u);
    k_denom<<<nbE256, 256, 0, stream>>>(logits, edge_dst, sorted, amax_u, denom, E);
    k_value<<<E / 32, 256, 0, stream>>>(msg_bf, edge_attr, w_lact_l, b_lin_act, w_dtp_v,
                                        w_linv_l, b_lin_v, logits, edge_dst, amax_u, denom,
                                        sorted, node);
    k_proj<<<N / 32, 256, 0, stream>>>(node, w_proj, b_proj, (float*)d_out);
}

// Round 13
// 403.035 us; speedup vs baseline: 1.0839x; 1.0839x over previous
//
#include <hip/hip_runtime.h>
#include <hip/hip_bf16.h>

#define C_   128
#define A_   4
#define S_   16
#define RH_  64
#define H_   8
#define AH_  256
#define OUT_ 128

typedef __attribute__((ext_vector_type(8))) short bf16x8;
typedef __attribute__((ext_vector_type(4))) float f32x4;

__device__ __forceinline__ float sigf(float x) { return 1.0f / (1.0f + __expf(-x)); }

__device__ __forceinline__ unsigned short f2bf(float x) {
    unsigned u = __float_as_uint(x);
    unsigned r = (u + 0x7fffu + ((u >> 16) & 1u)) >> 16;   // RNE
    return (unsigned short)r;
}
__device__ __forceinline__ float bf2f(unsigned short v) {
    return __uint_as_float((unsigned)v << 16);
}

// packed pair f32->bf16 (compiler emits v_cvt_pk_bf16_f32)
__device__ __forceinline__ unsigned pkbf(float a, float b) {
    union { __hip_bfloat162 h; unsigned u; } c;
    c.h = __float22bfloat162_rn(float2{a, b});
    return c.u;
}

// monotone float <-> uint mapping for atomicMax-based segment max
__device__ __forceinline__ unsigned enc(float x) {
    unsigned b = __float_as_uint(x);
    return (b & 0x80000000u) ? ~b : (b | 0x80000000u);
}
__device__ __forceinline__ float dec(unsigned u) {
    unsigned b = (u & 0x80000000u) ? (u & 0x7fffffffu) : ~u;
    return __uint_as_float(b);
}

// Pack f32 weight W[K][N] into bf16 fragment-linear layout for mfma_f32_16x16x32_bf16:
// out[((ct*(K/32)+ks)*64 + l)*8 + j] = W[ks*32 + (l>>4)*8 + j][ct*16 + (l&15)]
__global__ void k_pack(const float* __restrict__ W, short* __restrict__ out, int K, int N) {
    const int KS = K / 32;
    const int ct = blockIdx.x / KS, ks = blockIdx.x % KS;
    const int l = threadIdx.x, lr = l & 15, lg = l >> 4;
    bf16x8 v;
    #pragma unroll
    for (int j = 0; j < 8; j++)
        v[j] = (short)f2bf(W[(size_t)(ks * 32 + lg * 8 + j) * N + ct * 16 + lr]);
    *(bf16x8*)&out[((size_t)blockIdx.x * 64 + l) * 8] = v;
}

// Pack w_rad2 [64][512] as B'[k][c] with k = r*4+a (K=256), c in [0,128)
__global__ void k_pack_dtp(const float* __restrict__ W, short* __restrict__ out) {
    const int ct = blockIdx.x >> 3, ks = blockIdx.x & 7;
    const int l = threadIdx.x, lr = l & 15, lg = l >> 4;
    bf16x8 v;
    #pragma unroll
    for (int j = 0; j < 8; j++)
        v[j] = (short)f2bf(W[(size_t)(ks * 8 + lg * 2 + (j >> 2)) * 512 + (ct * 16 + lr) * 4 + (j & 3)]);
    *(bf16x8*)&out[((size_t)blockIdx.x * 64 + l) * 8] = v;
}

// CSR build: histogram, scan, fill (sorted edge list)
__global__ __launch_bounds__(256) void k_hist(
    const int* __restrict__ edge_dst, int* __restrict__ deg, int E)
{
    const int e = blockIdx.x * 256 + threadIdx.x;
    if (e < E) atomicAdd(&deg[edge_dst[e]], 1);
}

__global__ __launch_bounds__(1024) void k_scan(
    const int* __restrict__ deg, int* __restrict__ cursor, int N)
{
    __shared__ int part[1024];
    const int t = threadIdx.x;
    const int per = (N + 1023) / 1024;
    const int i0 = t * per;
    int s = 0;
    for (int i = 0; i < per; i++) { int idx = i0 + i; if (idx < N) s += deg[idx]; }
    part[t] = s;
    __syncthreads();
    for (int off = 1; off < 1024; off <<= 1) {
        int v = (t >= off) ? part[t - off] : 0;
        __syncthreads();
        part[t] += v;
        __syncthreads();
    }
    int excl = (t == 0) ? 0 : part[t - 1];
    for (int i = 0; i < per; i++) {
        int idx = i0 + i;
        if (idx < N) { cursor[idx] = excl; excl += deg[idx]; }
    }
}

__global__ __launch_bounds__(256) void k_fill(
    const int* __restrict__ edge_dst, int* __restrict__ cursor,
    int* __restrict__ sorted, int E)
{
    const int e = blockIdx.x * 256 + threadIdx.x;
    if (e < E) {
        const int pos = atomicAdd(&cursor[edge_dst[e]], 1);
        sorted[pos] = e;
    }
}

// Fused msg + alpha. 32 edges/block, 256 threads (4 waves), ~24.6KB LDS.
// (256,4): 128-VGPR budget. Local optimum (R8-R12): (256,6) spills; MFMA
// Phase A serializes; K-chunked fragments at (256,5) spill + double loads.
__global__ __launch_bounds__(256, 4) void k_msgalpha(
    const float* __restrict__ message, const float* __restrict__ edge_attr,
    const float* __restrict__ edge_scalars,
    const float* __restrict__ w_rad1, const float* __restrict__ b_rad1,
    const short* __restrict__ w_rad2_lin, const float* __restrict__ b_rad2,
    const short* __restrict__ w_alpha_lin, const float* __restrict__ b_alpha,
    const float* __restrict__ alpha_dot, const int* __restrict__ edge_dst,
    short* __restrict__ msg_bf, float* __restrict__ logits, unsigned* __restrict__ amax_u)
{
    __shared__ __align__(16) char smem[25216];
    short* Ap     = (short*)smem;                     // [32] rows x 512B, swz (r&31)<<4
    short* msg_s  = (short*)(smem + 16384);           // [32] rows x 256B, swz (r&15)<<4
    float* w1_s   = (float*)(smem + 16384);           // overlay [16][64]
    float* es_s   = (float*)(smem + 16384 + 4096);    // overlay [32][17]
    float* attr_s = (float*)(smem + 24576);           // [32][4]
    int*   dst_s  = (int*)(smem + 25088);             // [32]

    const int t = threadIdx.x;
    const long e0 = (long)blockIdx.x * 32;

    *(float4*)&w1_s[t * 4] = *(const float4*)&w_rad1[t * 4];
    if (t < 128) {
        const int r = t >> 2, s4 = (t & 3) * 4;
        *(float4*)&es_s[r * 17 + s4] = *(const float4*)&edge_scalars[(e0 + r) * S_ + s4];
    }
    if (t < 32) {
        *(float4*)&attr_s[t * 4] = *(const float4*)&edge_attr[(e0 + t) * A_];
        dst_s[t] = edge_dst[e0 + t];
    }
    __syncthreads();

    {   // Phase A: h = silu(es @ w_rad1 + b1); A'[r, 4c+a] = h[r,c]*attr[r,a]
        const int r = t & 31, o0 = (t >> 5) * 8;
        float acc[8];
        #pragma unroll
        for (int i = 0; i < 8; i++) acc[i] = b_rad1[o0 + i];
        #pragma unroll
        for (int s = 0; s < S_; s++) {
            const float ev = es_s[r * 17 + s];
            #pragma unroll
            for (int i = 0; i < 8; i++) acc[i] += ev * w1_s[s * 64 + o0 + i];
        }
        float h[8];
        #pragma unroll
        for (int i = 0; i < 8; i++) { const float x = acc[i]; h[i] = x * sigf(x); }
        const float4 a4 = *(const float4*)&attr_s[r * 4];
        char* base = (char*)Ap + r * 512;
        const int sw = (r & 31) << 4;
        #pragma unroll
        for (int c = 0; c < 4; c++) {
            const float h0 = h[2 * c], h1 = h[2 * c + 1];
            uint4 v;
            v.x = pkbf(h0 * a4.x, h0 * a4.y);
            v.y = pkbf(h0 * a4.z, h0 * a4.w);
            v.z = pkbf(h1 * a4.x, h1 * a4.y);
            v.w = pkbf(h1 * a4.z, h1 * a4.w);
            *(uint4*)(base + ((o0 * 8 + c * 16) ^ sw)) = v;
        }
    }
    __syncthreads();

    const int w = t >> 6, l = t & 63, lr = l & 15, lg = l >> 4;

    {   // Phase B: tp = A'(32x256) @ B'(256x128); msg = message * tp -> msg_s
        #pragma unroll
        for (int q = 0; q < 2; q++) {
            const int ct = w * 2 + q;
            bf16x8 bf[8];
            #pragma unroll
            for (int ks = 0; ks < 8; ks++)
                bf[ks] = *(const bf16x8*)&w_rad2_lin[((size_t)(ct * 8 + ks) * 64 + l) * 8];
            const int col = ct * 16 + lr;
            const float4 b2 = *(const float4*)&b_rad2[col * 4];
            #pragma unroll
            for (int rt = 0; rt < 2; rt++) {
                const int arow = rt * 16 + lr;
                const char* abase = (char*)Ap + arow * 512;
                const int asw = (arow & 31) << 4;
                bf16x8 af[8];
                #pragma unroll
                for (int ks = 0; ks < 8; ks++)
                    af[ks] = *(const bf16x8*)(abase + ((ks * 64 + lg * 16) ^ asw));
                f32x4 acc = {0.f, 0.f, 0.f, 0.f};
                #pragma unroll
                for (int ks = 0; ks < 8; ks++)
                    acc = __builtin_amdgcn_mfma_f32_16x16x32_bf16(af[ks], bf[ks], acc, 0, 0, 0);
                #pragma unroll
                for (int r = 0; r < 4; r++) {
                    const int row = rt * 16 + lg * 4 + r;
                    const float4 a4 = *(const float4*)&attr_s[row * 4];
                    const float badj = a4.x * b2.x + a4.y * b2.y + a4.z * b2.z + a4.w * b2.w;
                    const float m = message[(e0 + row) * C_ + col];
                    *(short*)((char*)msg_s + row * 256 + ((col * 2) ^ ((row & 15) << 4))) =
                        (short)f2bf(m * (acc[r] + badj));
                }
            }
        }
    }
    __syncthreads();

    {   // Phase C: msg_s -> global (linear bf16 rows)
        #pragma unroll
        for (int i = 0; i < 2; i++) {
            const int q = t + i * 256;
            const int row = q >> 4, ch = q & 15;
            const uint4 v = *(const uint4*)((char*)msg_s + row * 256 + ((ch * 16) ^ ((row & 15) << 4)));
            *(uint4*)((char*)msg_bf + ((e0 + row) * 256 + ch * 16)) = v;
        }
    }

    {   // Phase D: transposed alpha GEMM; wave w owns heads {2w, 2w+1}
        #pragma unroll
        for (int hq = 0; hq < 2; hq++) {
            const int hd = w * 2 + hq;
            bf16x8 waf[2][4];
            float4 ba4[2], ad4[2];
            #pragma unroll
            for (int q = 0; q < 2; q++) {
                const int ctw = hd * 2 + q;
                #pragma unroll
                for (int ks = 0; ks < 4; ks++)
                    waf[q][ks] = *(const bf16x8*)&w_alpha_lin[((size_t)(ctw * 4 + ks) * 64 + l) * 8];
                ba4[q] = *(const float4*)&b_alpha[ctw * 16 + lg * 4];
                ad4[q] = *(const float4*)&alpha_dot[ctw * 16 + lg * 4];
            }
            #pragma unroll
            for (int ct = 0; ct < 2; ct++) {
                const int erow = ct * 16 + lr;
                const char* mbase = (char*)msg_s + erow * 256;
                const int msw = (erow & 15) << 4;
                bf16x8 mb[4];
                #pragma unroll
                for (int ks = 0; ks < 4; ks++)
                    mb[ks] = *(const bf16x8*)(mbase + ((ks * 64 + lg * 16) ^ msw));
                float s = 0.f;
                #pragma unroll
                for (int q = 0; q < 2; q++) {
                    f32x4 acc = {0.f, 0.f, 0.f, 0.f};
                    #pragma unroll
                    for (int ks = 0; ks < 4; ks++)
                        acc = __builtin_amdgcn_mfma_f32_16x16x32_bf16(waf[q][ks], mb[ks], acc, 0, 0, 0);
                    #pragma unroll
                    for (int r = 0; r < 4; r++) {
                        const float x = acc[r] + ((const float*)&ba4[q])[r];
                        const float y = x * (0.2f + 0.8f * sigf(x));   // SmoothLeakyReLU a=0.2
                        s += y * ((const float*)&ad4[q])[r];
                    }
                }
                s += __shfl_xor(s, 16);
                s += __shfl_xor(s, 32);
                if (lg == 0) {
                    const long e = e0 + ct * 16 + lr;
                    logits[e * H_ + hd] = s;
                    atomicMax(&amax_u[dst_s[ct * 16 + lr] * H_ + hd], enc(s));
                }
            }
        }
    }
}

// K3: denom via run-length over 8 sorted edges per thread (1 head each).
// Atomics drop ~8x vs per-(edge,head); reads gather but 8 lanes share rows.
__global__ __launch_bounds__(256) void k_denom(
    const float* __restrict__ logits, const int* __restrict__ edge_dst,
    const int* __restrict__ sorted, const unsigned* __restrict__ amax_u,
    float* __restrict__ denom, int E)
{
    const int idx = blockIdx.x * 256 + threadIdx.x;
    if (idx >= E) return;
    const int g = idx >> 3, h = idx & 7;
    int nprev = -1; float run = 0.f, am = 0.f;
    #pragma unroll 1
    for (int e = 0; e < 8; e++) {
        const int eid = sorted[g * 8 + e];
        const int n = edge_dst[eid];
        if (n != nprev) {
            if (nprev >= 0) atomicAdd(&denom[nprev * H_ + h], run);
            nprev = n; run = 0.f;
            am = dec(amax_u[n * H_ + h]);
        }
        run += __expf(logits[(size_t)eid * H_ + h] - am);
    }
    atomicAdd(&denom[nprev * H_ + h], run);
}

// K4: dst-sorted edges, 32 per block, 256 threads (4 waves), ~19KB LDS.
// val2 bf16 [32][264] overlays staging -> ~5 blocks/CU. Gate GEMM: each wave
// owns col-tiles {2w, 2w+1}.
__global__ __launch_bounds__(256, 5) void k_value(
    const short* __restrict__ msg_bf, const float* __restrict__ edge_attr,
    const short* __restrict__ w_lin_act_lin, const float* __restrict__ b_lin_act,
    const float* __restrict__ w_dtp_v,
    const short* __restrict__ w_lin_v_lin, const float* __restrict__ b_lin_v,
    const float* __restrict__ logits, const int* __restrict__ edge_dst,
    const unsigned* __restrict__ amax_u, const float* __restrict__ denom,
    const int* __restrict__ sorted, float* __restrict__ node)
{
    __shared__ __align__(16) char pool[16896];   // max(a_s 8K + v_s 8K, val2 32x264 bf16)
    __shared__ float attr_s[32][4];
    __shared__ float wgt_s[32][H_];
    __shared__ int   dst_s[32];
    __shared__ int   eid_s[32];
    short* a_s  = (short*)pool;            // [32] rows x 256B, swizzle (row&15)<<4
    short* v_s  = (short*)(pool + 8192);   // [32] rows x 256B, swizzle (row&15)<<4
    short* val2 = (short*)pool;            // [32][264] bf16 overlay

    const int t = threadIdx.x;
    const int b0 = blockIdx.x * 32;

    if (t < 32) {
        const int e = sorted[b0 + t];
        eid_s[t] = e;
        dst_s[t] = edge_dst[e];
        *(float4*)&attr_s[t][0] = *(const float4*)&edge_attr[(long)e * A_];
    }
    __syncthreads();
    #pragma unroll
    for (int i = 0; i < 2; i++) {   // gather msg rows -> swizzled LDS
        const int q = t + i * 256;
        const int row = q >> 4, ch = q & 15;
        const uint4 v = *(const uint4*)((const char*)msg_bf + ((long)eid_s[row] * 256 + ch * 16));
        *(uint4*)((char*)a_s + row * 256 + ((ch * 16) ^ ((row & 15) << 4))) = v;
    }
    {   // softmax weights, one (el,h) per thread
        const int el = t >> 3, h = t & 7;
        const long e = eid_s[el];
        const int n = dst_s[el];
        const float am = dec(amax_u[n * H_ + h]);
        const float d  = denom[n * H_ + h];
        wgt_s[el][h] = __expf(logits[e * H_ + h] - am) / (d + 1e-16f);
    }
    __syncthreads();

    const int w = t >> 6, l = t & 63, lr = l & 15, lg = l >> 4;
    {   // gate GEMM: wave w owns col-tiles {2w, 2w+1} (32 of 128 cols), 32 rows
        bf16x8 af[2][4];
        #pragma unroll
        for (int rt = 0; rt < 2; rt++)
            #pragma unroll
            for (int ks = 0; ks < 4; ks++) {
                const int arow = rt * 16 + lr;
                af[rt][ks] = *(bf16x8*)((char*)a_s + arow * 256 + ((ks * 64 + lg * 16) ^ ((arow & 15) << 4)));
            }
        #pragma unroll
        for (int q = 0; q < 2; q++) {
            const int ct = w * 2 + q;
            bf16x8 bfg[4];
            #pragma unroll
            for (int ks = 0; ks < 4; ks++)
                bfg[ks] = *(const bf16x8*)&w_lin_act_lin[((size_t)(ct * 4 + ks) * 64 + l) * 8];
            const int col = ct * 16 + lr;
            const float bb = b_lin_act[col];
            const float4 wv = *(const float4*)&w_dtp_v[col * 4];
            #pragma unroll
            for (int rt = 0; rt < 2; rt++) {
                f32x4 acc = {0.f, 0.f, 0.f, 0.f};
                #pragma unroll
                for (int ks = 0; ks < 4; ks++)
                    acc = __builtin_amdgcn_mfma_f32_16x16x32_bf16(af[rt][ks], bfg[ks], acc, 0, 0, 0);
                #pragma unroll
                for (int r = 0; r < 4; r++) {
                    const int row = rt * 16 + lg * 4 + r;
                    float x = acc[r] + bb;
                    x = x * sigf(x);
                    const float4 a4 = *(const float4*)&attr_s[row][0];
                    const float dv = wv.x * a4.x + wv.y * a4.y + wv.z * a4.z + wv.w * a4.w;
                    *(short*)((char*)v_s + row * 256 + ((col * 2) ^ ((row & 15) << 4))) =
                        (short)f2bf(x * dv);
                }
            }
        }
    }
    __syncthreads();

    bf16x8 vf[2][4];
    #pragma unroll
    for (int rt = 0; rt < 2; rt++)
        #pragma unroll
        for (int ks = 0; ks < 4; ks++) {
            const int row = rt * 16 + lr;
            vf[rt][ks] = *(bf16x8*)((char*)v_s + row * 256 + ((ks * 64 + lg * 16) ^ ((row & 15) << 4)));
        }
    __syncthreads();   // all v_s reads done; pool reusable as val2

    #pragma unroll
    for (int q = 0; q < 4; q++) {   // value GEMM: wave w owns col-tiles w*4..w*4+3
        const int ct = w * 4 + q;
        bf16x8 bf[4];
        #pragma unroll
        for (int ks = 0; ks < 4; ks++)
            bf[ks] = *(const bf16x8*)&w_lin_v_lin[((size_t)(ct * 4 + ks) * 64 + l) * 8];
        const int col = ct * 16 + lr;
        const float bb = b_lin_v[col];
        #pragma unroll
        for (int rt = 0; rt < 2; rt++) {
            f32x4 acc = {0.f, 0.f, 0.f, 0.f};
            #pragma unroll
            for (int ks = 0; ks < 4; ks++)
                acc = __builtin_amdgcn_mfma_f32_16x16x32_bf16(vf[rt][ks], bf[ks], acc, 0, 0, 0);
            #pragma unroll
            for (int r = 0; r < 4; r++) {
                const int row = rt * 16 + lg * 4 + r;
                val2[row * 264 + col] = (short)f2bf((acc[r] + bb) * wgt_s[row][col >> 5]);
            }
        }
    }
    __syncthreads();
    {   // run-length reduce by dst; thread owns channel t over all 32 edges
        const int c = t;
        float run = 0.f;
        int s = 0;
        #pragma unroll 1
        for (int e = 0; e < 32; e++) {
            run += bf2f((unsigned short)val2[e * 264 + c]);
            const bool end = (e == 31) || (dst_s[e + 1] != dst_s[e]);
            if (end) {
                float* np = node + (long)dst_s[e] * AH_ + c;
                if (s == 0 || e == 31) atomicAdd(np, run);
                else *np = run;
                run = 0.f; s = e + 1;
            }
        }
    }
}

// K5: out = node @ w_proj + b_proj
__global__ __launch_bounds__(256) void k_proj(
    const float* __restrict__ node, const float* __restrict__ w_proj,
    const float* __restrict__ b_proj, float* __restrict__ out)
{
    __shared__ float node_s[32][AH_];
    const int t = threadIdx.x;
    const long n0 = (long)blockIdx.x * 32;
    #pragma unroll
    for (int i = 0; i < 8; i++) {
        const int idx = t + i * 256;
        const int nl = idx >> 6, c4 = (idx & 63) * 4;
        *(float4*)&node_s[nl][c4] = *(const float4*)&node[(n0 + nl) * AH_ + c4];
    }
    __syncthreads();
    const int j0 = (t & 31) * 4;
    const int g  = t >> 5;
    float4 acc4[4];
    const float4 b = *(const float4*)&b_proj[j0];
    #pragma unroll
    for (int i = 0; i < 4; i++) acc4[i] = b;
    const float* wp = w_proj + j0;
    for (int c4 = 0; c4 < 64; c4++) {
        const float4 w0 = *(const float4*)&wp[(c4 * 4 + 0) * OUT_];
        const float4 w1 = *(const float4*)&wp[(c4 * 4 + 1) * OUT_];
        const float4 w2 = *(const float4*)&wp[(c4 * 4 + 2) * OUT_];
        const float4 w3 = *(const float4*)&wp[(c4 * 4 + 3) * OUT_];
        #pragma unroll
        for (int i = 0; i < 4; i++) {
            const float4 nv = *(const float4*)&node_s[g * 4 + i][c4 * 4];
            acc4[i].x += nv.x * w0.x + nv.y * w1.x + nv.z * w2.x + nv.w * w3.x;
            acc4[i].y += nv.x * w0.y + nv.y * w1.y + nv.z * w2.y + nv.w * w3.y;
            acc4[i].z += nv.x * w0.z + nv.y * w1.z + nv.z * w2.z + nv.w * w3.z;
            acc4[i].w += nv.x * w0.w + nv.y * w1.w + nv.z * w2.w + nv.w * w3.w;
        }
    }
    #pragma unroll
    for (int i = 0; i < 4; i++) {
        const long n = n0 + g * 4 + i;
        *(float4*)&out[n * OUT_ + j0] = acc4[i];
    }
}

extern "C" void kernel_launch(void* const* d_in, const int* in_sizes, int n_in,
                              void* d_out, int out_size, void* d_ws, size_t ws_size,
                              hipStream_t stream)
{
    const float* message      = (const float*)d_in[0];
    const float* edge_attr    = (const float*)d_in[1];
    const float* edge_scalars = (const float*)d_in[2];
    const float* w_rad1       = (const float*)d_in[3];
    const float* b_rad1       = (const float*)d_in[4];
    const float* w_rad2       = (const float*)d_in[5];
    const float* b_rad2       = (const float*)d_in[6];
    const float* w_dtp_v      = (const float*)d_in[7];
    const float* w_lin_act    = (const float*)d_in[8];
    const float* b_lin_act    = (const float*)d_in[9];
    const float* w_alpha      = (const float*)d_in[10];
    const float* b_alpha      = (const float*)d_in[11];
    const float* w_lin_v      = (const float*)d_in[12];
    const float* b_lin_v      = (const float*)d_in[13];
    const float* alpha_dot    = (const float*)d_in[14];
    const float* w_proj       = (const float*)d_in[15];
    const float* b_proj       = (const float*)d_in[16];
    const int*   edge_dst     = (const int*)d_in[17];

    const int E = in_sizes[0] / C_;
    const int N = out_size / OUT_;

    // ws layout (zeroed region first):
    // [node N*256 f32][amax N*8 u32][denom N*8 f32][deg N i32] |
    // [cursor N][sorted E][wpacks][msg_bf E*128 s][logits E*8 f32]
    char* ws = (char*)d_ws;
    float*    node     = (float*)ws;
    unsigned* amax_u   = (unsigned*)(node + (size_t)N * AH_);
    float*    denom    = (float*)(amax_u + (size_t)N * H_);
    int*      deg      = (int*)(denom + (size_t)N * H_);
    int*      cursor   = deg + N;
    int*      sorted   = cursor + N;
    short*    w_rad2_l = (short*)(sorted + E);
    short*    w_alph_l = w_rad2_l + 64 * 512;
    short*    w_lact_l = w_alph_l + 128 * 256;
    short*    w_linv_l = w_lact_l + 128 * 128;
    short*    msg_bf   = w_linv_l + 128 * 256;
    float*    logits   = (float*)(msg_bf + (size_t)E * C_);

    hipMemsetAsync(d_ws, 0, (size_t)N * (AH_ + 2 * H_ + 1) * 4, stream);

    const int nbE256 = (E + 255) / 256;
    k_pack_dtp<<<64, 64, 0, stream>>>(w_rad2, w_rad2_l);
    k_pack<<<(256/16)*(128/32), 64, 0, stream>>>(w_alpha,   w_alph_l, 128, 256);
    k_pack<<<(128/16)*(128/32), 64, 0, stream>>>(w_lin_act, w_lact_l, 128, 128);
    k_pack<<<(256/16)*(128/32), 64, 0, stream>>>(w_lin_v,   w_linv_l, 128, 256);
    k_hist<<<nbE256, 256, 0, stream>>>(edge_dst, deg, E);
    k_scan<<<1, 1024, 0, stream>>>(deg, cursor, N);
    k_fill<<<nbE256, 256, 0, stream>>>(edge_dst, cursor, sorted, E);
    k_msgalpha<<<E / 32, 256, 0, stream>>>(message, edge_attr, edge_scalars,
                                           w_rad1, b_rad1, w_rad2_l, b_rad2,
                                           w_alph_l, b_alpha, alpha_dot, edge_dst,
                                           msg_bf, logits, amax_u);
    k_denom<<<nbE256, 256, 0, stream>>>(logits, edge_dst, sorted, amax_u, denom, E);
    k_value<<<E / 32, 256, 0, stream>>>(msg_bf, edge_attr, w_lact_l, b_lin_act, w_dtp_v,
                                        w_linv_l, b_lin_v, logits, edge_dst, amax_u, denom,
                                        sorted, node);
    k_proj<<<N / 32, 256, 0, stream>>>(node, w_proj, b_proj, (float*)d_out);
}

// Round 14
// 397.456 us; speedup vs baseline: 1.0991x; 1.0140x over previous
//
#include <hip/hip_runtime.h>
#include <hip/hip_bf16.h>

#define C_   128
#define A_   4
#define S_   16
#define RH_  64
#define H_   8
#define AH_  256
#define OUT_ 128

typedef __attribute__((ext_vector_type(8))) short bf16x8;
typedef __attribute__((ext_vector_type(4))) float f32x4;

__device__ __forceinline__ float sigf(float x) { return 1.0f / (1.0f + __expf(-x)); }

__device__ __forceinline__ unsigned short f2bf(float x) {
    unsigned u = __float_as_uint(x);
    unsigned r = (u + 0x7fffu + ((u >> 16) & 1u)) >> 16;   // RNE
    return (unsigned short)r;
}
__device__ __forceinline__ float bf2f(unsigned short v) {
    return __uint_as_float((unsigned)v << 16);
}

// packed pair f32->bf16 (compiler emits v_cvt_pk_bf16_f32)
__device__ __forceinline__ unsigned pkbf(float a, float b) {
    union { __hip_bfloat162 h; unsigned u; } c;
    c.h = __float22bfloat162_rn(float2{a, b});
    return c.u;
}

// monotone float <-> uint mapping for atomicMax-based segment max
__device__ __forceinline__ unsigned enc(float x) {
    unsigned b = __float_as_uint(x);
    return (b & 0x80000000u) ? ~b : (b | 0x80000000u);
}
__device__ __forceinline__ float dec(unsigned u) {
    unsigned b = (u & 0x80000000u) ? (u & 0x7fffffffu) : ~u;
    return __uint_as_float(b);
}

// Pack f32 weight W[K][N] into bf16 fragment-linear layout for mfma_f32_16x16x32_bf16:
// out[((ct*(K/32)+ks)*64 + l)*8 + j] = W[ks*32 + (l>>4)*8 + j][ct*16 + (l&15)]
__global__ void k_pack(const float* __restrict__ W, short* __restrict__ out, int K, int N) {
    const int KS = K / 32;
    const int ct = blockIdx.x / KS, ks = blockIdx.x % KS;
    const int l = threadIdx.x, lr = l & 15, lg = l >> 4;
    bf16x8 v;
    #pragma unroll
    for (int j = 0; j < 8; j++)
        v[j] = (short)f2bf(W[(size_t)(ks * 32 + lg * 8 + j) * N + ct * 16 + lr]);
    *(bf16x8*)&out[((size_t)blockIdx.x * 64 + l) * 8] = v;
}

// Pack w_rad2 [64][512] as B'[k][c] with k = r*4+a (K=256), c in [0,128)
__global__ void k_pack_dtp(const float* __restrict__ W, short* __restrict__ out) {
    const int ct = blockIdx.x >> 3, ks = blockIdx.x & 7;
    const int l = threadIdx.x, lr = l & 15, lg = l >> 4;
    bf16x8 v;
    #pragma unroll
    for (int j = 0; j < 8; j++)
        v[j] = (short)f2bf(W[(size_t)(ks * 8 + lg * 2 + (j >> 2)) * 512 + (ct * 16 + lr) * 4 + (j & 3)]);
    *(bf16x8*)&out[((size_t)blockIdx.x * 64 + l) * 8] = v;
}

// CSR build: histogram, scan, fill (sorted edge list)
__global__ __launch_bounds__(256) void k_hist(
    const int* __restrict__ edge_dst, int* __restrict__ deg, int E)
{
    const int e = blockIdx.x * 256 + threadIdx.x;
    if (e < E) atomicAdd(&deg[edge_dst[e]], 1);
}

__global__ __launch_bounds__(1024) void k_scan(
    const int* __restrict__ deg, int* __restrict__ cursor, int N)
{
    __shared__ int part[1024];
    const int t = threadIdx.x;
    const int per = (N + 1023) / 1024;
    const int i0 = t * per;
    int s = 0;
    for (int i = 0; i < per; i++) { int idx = i0 + i; if (idx < N) s += deg[idx]; }
    part[t] = s;
    __syncthreads();
    for (int off = 1; off < 1024; off <<= 1) {
        int v = (t >= off) ? part[t - off] : 0;
        __syncthreads();
        part[t] += v;
        __syncthreads();
    }
    int excl = (t == 0) ? 0 : part[t - 1];
    for (int i = 0; i < per; i++) {
        int idx = i0 + i;
        if (idx < N) { cursor[idx] = excl; excl += deg[idx]; }
    }
}

__global__ __launch_bounds__(256) void k_fill(
    const int* __restrict__ edge_dst, int* __restrict__ cursor,
    int* __restrict__ sorted, int E)
{
    const int e = blockIdx.x * 256 + threadIdx.x;
    if (e < E) {
        const int pos = atomicAdd(&cursor[edge_dst[e]], 1);
        sorted[pos] = e;
    }
}

// Fused msg + alpha. 64 edges/block, 512 threads (8 waves), ~50.4KB LDS.
// R5-measured shape: 178us (vs 191us at 32-edge) -- 64-edge amortizes the
// per-wave weight-fragment loads over 2x rows at the same occupancy.
__global__ __launch_bounds__(512, 4) void k_msgalpha(
    const float* __restrict__ message, const float* __restrict__ edge_attr,
    const float* __restrict__ edge_scalars,
    const float* __restrict__ w_rad1, const float* __restrict__ b_rad1,
    const short* __restrict__ w_rad2_lin, const float* __restrict__ b_rad2,
    const short* __restrict__ w_alpha_lin, const float* __restrict__ b_alpha,
    const float* __restrict__ alpha_dot, const int* __restrict__ edge_dst,
    short* __restrict__ msg_bf, float* __restrict__ logits, unsigned* __restrict__ amax_u)
{
    __shared__ __align__(16) char smem[50432];
    short* Ap     = (short*)smem;                       // A' row stride 512B
    short* msg_s  = (short*)(smem + 32768);             // row stride 256B
    float* w1_s   = (float*)(smem + 32768);             // [16][64] overlay
    float* es_s   = (float*)(smem + 32768 + 4096);      // [64][17] overlay
    float* attr_s = (float*)(smem + 49152);             // [64][4]
    int*   dst_s  = (int*)(smem + 50176);               // [64]

    const int t = threadIdx.x;
    const long e0 = (long)blockIdx.x * 64;

    if (t < 256) {
        *(float4*)&w1_s[t * 4] = *(const float4*)&w_rad1[t * 4];
    } else {
        const int i = t - 256, r = i >> 2, s4 = (i & 3) * 4;
        *(float4*)&es_s[r * 17 + s4] = *(const float4*)&edge_scalars[(e0 + r) * S_ + s4];
    }
    if (t < 64) {
        *(float4*)&attr_s[t * 4] = *(const float4*)&edge_attr[(e0 + t) * A_];
        dst_s[t] = edge_dst[e0 + t];
    }
    __syncthreads();

    {   // Phase A: h = silu(es @ w_rad1 + b1); A'[r, 4c+a] = h[r,c]*attr[r,a]
        const int r = t & 63, o0 = (t >> 6) * 8;
        float acc[8];
        #pragma unroll
        for (int i = 0; i < 8; i++) acc[i] = b_rad1[o0 + i];
        #pragma unroll
        for (int s = 0; s < S_; s++) {
            const float ev = es_s[r * 17 + s];
            #pragma unroll
            for (int i = 0; i < 8; i++) acc[i] += ev * w1_s[s * 64 + o0 + i];
        }
        float h[8];
        #pragma unroll
        for (int i = 0; i < 8; i++) { const float x = acc[i]; h[i] = x * sigf(x); }
        const float4 a4 = *(const float4*)&attr_s[r * 4];
        char* base = (char*)Ap + r * 512;
        const int sw = (r & 31) << 4;
        #pragma unroll
        for (int c = 0; c < 4; c++) {
            const float h0 = h[2 * c], h1 = h[2 * c + 1];
            uint4 v;
            v.x = pkbf(h0 * a4.x, h0 * a4.y);
            v.y = pkbf(h0 * a4.z, h0 * a4.w);
            v.z = pkbf(h1 * a4.x, h1 * a4.y);
            v.w = pkbf(h1 * a4.z, h1 * a4.w);
            *(uint4*)(base + ((o0 * 8 + c * 16) ^ sw)) = v;
        }
    }
    __syncthreads();

    const int w = t >> 6, l = t & 63, lr = l & 15, lg = l >> 4;

    {   // Phase B: tp = A'(64x256) @ B'(256x128); msg = message * tp -> msg_s
        bf16x8 bf[8];
        #pragma unroll
        for (int ks = 0; ks < 8; ks++)
            bf[ks] = *(const bf16x8*)&w_rad2_lin[((size_t)(w * 8 + ks) * 64 + l) * 8];
        const int col = w * 16 + lr;
        const float4 b2 = *(const float4*)&b_rad2[col * 4];
        #pragma unroll 1
        for (int rt = 0; rt < 4; rt++) {
            const int arow = rt * 16 + lr;
            const char* abase = (char*)Ap + arow * 512;
            const int asw = (arow & 31) << 4;
            bf16x8 af[8];
            #pragma unroll
            for (int ks = 0; ks < 8; ks++)
                af[ks] = *(const bf16x8*)(abase + ((ks * 64 + lg * 16) ^ asw));
            f32x4 acc = {0.f, 0.f, 0.f, 0.f};
            #pragma unroll
            for (int ks = 0; ks < 8; ks++)
                acc = __builtin_amdgcn_mfma_f32_16x16x32_bf16(af[ks], bf[ks], acc, 0, 0, 0);
            #pragma unroll
            for (int r = 0; r < 4; r++) {
                const int row = rt * 16 + lg * 4 + r;
                const float4 a4 = *(const float4*)&attr_s[row * 4];
                const float badj = a4.x * b2.x + a4.y * b2.y + a4.z * b2.z + a4.w * b2.w;
                const float m = message[(e0 + row) * C_ + col];
                *(short*)((char*)msg_s + row * 256 + ((col * 2) ^ ((row & 15) << 4))) =
                    (short)f2bf(m * (acc[r] + badj));
            }
        }
    }
    __syncthreads();

    {   // Phase C: msg_s -> global (linear bf16 rows)
        #pragma unroll
        for (int i = 0; i < 2; i++) {
            const int q = t + i * 512;
            const int row = q >> 4, ch = q & 15;
            const uint4 v = *(const uint4*)((char*)msg_s + row * 256 + ((ch * 16) ^ ((row & 15) << 4)));
            *(uint4*)((char*)msg_bf + ((e0 + row) * 256 + ch * 16)) = v;
        }
    }

    {   // Phase D: wave w computes head w for all 64 edges (transposed GEMM)
        bf16x8 waf[2][4];
        float4 ba4[2], ad4[2];
        #pragma unroll
        for (int q = 0; q < 2; q++) {
            const int rt = w * 2 + q;
            #pragma unroll
            for (int ks = 0; ks < 4; ks++)
                waf[q][ks] = *(const bf16x8*)&w_alpha_lin[((size_t)(rt * 4 + ks) * 64 + l) * 8];
            ba4[q] = *(const float4*)&b_alpha[rt * 16 + lg * 4];
            ad4[q] = *(const float4*)&alpha_dot[rt * 16 + lg * 4];
        }
        #pragma unroll 1
        for (int ct = 0; ct < 4; ct++) {
            const int erow = ct * 16 + lr;
            const char* mbase = (char*)msg_s + erow * 256;
            const int msw = (erow & 15) << 4;
            bf16x8 mb[4];
            #pragma unroll
            for (int ks = 0; ks < 4; ks++)
                mb[ks] = *(const bf16x8*)(mbase + ((ks * 64 + lg * 16) ^ msw));
            float s = 0.f;
            #pragma unroll
            for (int q = 0; q < 2; q++) {
                f32x4 acc = {0.f, 0.f, 0.f, 0.f};
                #pragma unroll
                for (int ks = 0; ks < 4; ks++)
                    acc = __builtin_amdgcn_mfma_f32_16x16x32_bf16(waf[q][ks], mb[ks], acc, 0, 0, 0);
                #pragma unroll
                for (int r = 0; r < 4; r++) {
                    const float x = acc[r] + ((const float*)&ba4[q])[r];
                    const float y = x * (0.2f + 0.8f * sigf(x));   // SmoothLeakyReLU a=0.2
                    s += y * ((const float*)&ad4[q])[r];
                }
            }
            s += __shfl_xor(s, 16);
            s += __shfl_xor(s, 32);
            if (lg == 0) {
                const long e = e0 + ct * 16 + lr;
                logits[e * H_ + w] = s;
                atomicMax(&amax_u[dst_s[ct * 16 + lr] * H_ + w], enc(s));
            }
        }
    }
}

// K3: denom via run-length over 8 sorted edges per thread (1 head each).
__global__ __launch_bounds__(256) void k_denom(
    const float* __restrict__ logits, const int* __restrict__ edge_dst,
    const int* __restrict__ sorted, const unsigned* __restrict__ amax_u,
    float* __restrict__ denom, int E)
{
    const int idx = blockIdx.x * 256 + threadIdx.x;
    if (idx >= E) return;
    const int g = idx >> 3, h = idx & 7;
    int nprev = -1; float run = 0.f, am = 0.f;
    #pragma unroll 1
    for (int e = 0; e < 8; e++) {
        const int eid = sorted[g * 8 + e];
        const int n = edge_dst[eid];
        if (n != nprev) {
            if (nprev >= 0) atomicAdd(&denom[nprev * H_ + h], run);
            nprev = n; run = 0.f;
            am = dec(amax_u[n * H_ + h]);
        }
        run += __expf(logits[(size_t)eid * H_ + h] - am);
    }
    atomicAdd(&denom[nprev * H_ + h], run);
}

// K4: dst-sorted edges, 32 per block, 256 threads (4 waves), ~19KB LDS.
// val2 bf16 [32][264] overlays staging -> ~5 blocks/CU. Gate GEMM: each wave
// owns col-tiles {2w, 2w+1}.
__global__ __launch_bounds__(256, 5) void k_value(
    const short* __restrict__ msg_bf, const float* __restrict__ edge_attr,
    const short* __restrict__ w_lin_act_lin, const float* __restrict__ b_lin_act,
    const float* __restrict__ w_dtp_v,
    const short* __restrict__ w_lin_v_lin, const float* __restrict__ b_lin_v,
    const float* __restrict__ logits, const int* __restrict__ edge_dst,
    const unsigned* __restrict__ amax_u, const float* __restrict__ denom,
    const int* __restrict__ sorted, float* __restrict__ node)
{
    __shared__ __align__(16) char pool[16896];   // max(a_s 8K + v_s 8K, val2 32x264 bf16)
    __shared__ float attr_s[32][4];
    __shared__ float wgt_s[32][H_];
    __shared__ int   dst_s[32];
    __shared__ int   eid_s[32];
    short* a_s  = (short*)pool;            // [32] rows x 256B, swizzle (row&15)<<4
    short* v_s  = (short*)(pool + 8192);   // [32] rows x 256B, swizzle (row&15)<<4
    short* val2 = (short*)pool;            // [32][264] bf16 overlay

    const int t = threadIdx.x;
    const int b0 = blockIdx.x * 32;

    if (t < 32) {
        const int e = sorted[b0 + t];
        eid_s[t] = e;
        dst_s[t] = edge_dst[e];
        *(float4*)&attr_s[t][0] = *(const float4*)&edge_attr[(long)e * A_];
    }
    __syncthreads();
    #pragma unroll
    for (int i = 0; i < 2; i++) {   // gather msg rows -> swizzled LDS
        const int q = t + i * 256;
        const int row = q >> 4, ch = q & 15;
        const uint4 v = *(const uint4*)((const char*)msg_bf + ((long)eid_s[row] * 256 + ch * 16));
        *(uint4*)((char*)a_s + row * 256 + ((ch * 16) ^ ((row & 15) << 4))) = v;
    }
    {   // softmax weights, one (el,h) per thread
        const int el = t >> 3, h = t & 7;
        const long e = eid_s[el];
        const int n = dst_s[el];
        const float am = dec(amax_u[n * H_ + h]);
        const float d  = denom[n * H_ + h];
        wgt_s[el][h] = __expf(logits[e * H_ + h] - am) / (d + 1e-16f);
    }
    __syncthreads();

    const int w = t >> 6, l = t & 63, lr = l & 15, lg = l >> 4;
    {   // gate GEMM: wave w owns col-tiles {2w, 2w+1} (32 of 128 cols), 32 rows
        bf16x8 af[2][4];
        #pragma unroll
        for (int rt = 0; rt < 2; rt++)
            #pragma unroll
            for (int ks = 0; ks < 4; ks++) {
                const int arow = rt * 16 + lr;
                af[rt][ks] = *(bf16x8*)((char*)a_s + arow * 256 + ((ks * 64 + lg * 16) ^ ((arow & 15) << 4)));
            }
        #pragma unroll
        for (int q = 0; q < 2; q++) {
            const int ct = w * 2 + q;
            bf16x8 bfg[4];
            #pragma unroll
            for (int ks = 0; ks < 4; ks++)
                bfg[ks] = *(const bf16x8*)&w_lin_act_lin[((size_t)(ct * 4 + ks) * 64 + l) * 8];
            const int col = ct * 16 + lr;
            const float bb = b_lin_act[col];
            const float4 wv = *(const float4*)&w_dtp_v[col * 4];
            #pragma unroll
            for (int rt = 0; rt < 2; rt++) {
                f32x4 acc = {0.f, 0.f, 0.f, 0.f};
                #pragma unroll
                for (int ks = 0; ks < 4; ks++)
                    acc = __builtin_amdgcn_mfma_f32_16x16x32_bf16(af[rt][ks], bfg[ks], acc, 0, 0, 0);
                #pragma unroll
                for (int r = 0; r < 4; r++) {
                    const int row = rt * 16 + lg * 4 + r;
                    float x = acc[r] + bb;
                    x = x * sigf(x);
                    const float4 a4 = *(const float4*)&attr_s[row][0];
                    const float dv = wv.x * a4.x + wv.y * a4.y + wv.z * a4.z + wv.w * a4.w;
                    *(short*)((char*)v_s + row * 256 + ((col * 2) ^ ((row & 15) << 4))) =
                        (short)f2bf(x * dv);
                }
            }
        }
    }
    __syncthreads();

    bf16x8 vf[2][4];
    #pragma unroll
    for (int rt = 0; rt < 2; rt++)
        #pragma unroll
        for (int ks = 0; ks < 4; ks++) {
            const int row = rt * 16 + lr;
            vf[rt][ks] = *(bf16x8*)((char*)v_s + row * 256 + ((ks * 64 + lg * 16) ^ ((row & 15) << 4)));
        }
    __syncthreads();   // all v_s reads done; pool reusable as val2

    #pragma unroll
    for (int q = 0; q < 4; q++) {   // value GEMM: wave w owns col-tiles w*4..w*4+3
        const int ct = w * 4 + q;
        bf16x8 bf[4];
        #pragma unroll
        for (int ks = 0; ks < 4; ks++)
            bf[ks] = *(const bf16x8*)&w_lin_v_lin[((size_t)(ct * 4 + ks) * 64 + l) * 8];
        const int col = ct * 16 + lr;
        const float bb = b_lin_v[col];
        #pragma unroll
        for (int rt = 0; rt < 2; rt++) {
            f32x4 acc = {0.f, 0.f, 0.f, 0.f};
            #pragma unroll
            for (int ks = 0; ks < 4; ks++)
                acc = __builtin_amdgcn_mfma_f32_16x16x32_bf16(vf[rt][ks], bf[ks], acc, 0, 0, 0);
            #pragma unroll
            for (int r = 0; r < 4; r++) {
                const int row = rt * 16 + lg * 4 + r;
                val2[row * 264 + col] = (short)f2bf((acc[r] + bb) * wgt_s[row][col >> 5]);
            }
        }
    }
    __syncthreads();
    {   // run-length reduce by dst; thread owns channel t over all 32 edges
        const int c = t;
        float run = 0.f;
        int s = 0;
        #pragma unroll 1
        for (int e = 0; e < 32; e++) {
            run += bf2f((unsigned short)val2[e * 264 + c]);
            const bool end = (e == 31) || (dst_s[e + 1] != dst_s[e]);
            if (end) {
                float* np = node + (long)dst_s[e] * AH_ + c;
                if (s == 0 || e == 31) atomicAdd(np, run);
                else *np = run;
                run = 0.f; s = e + 1;
            }
        }
    }
}

// K5: out = node @ w_proj + b_proj
__global__ __launch_bounds__(256) void k_proj(
    const float* __restrict__ node, const float* __restrict__ w_proj,
    const float* __restrict__ b_proj, float* __restrict__ out)
{
    __shared__ float node_s[32][AH_];
    const int t = threadIdx.x;
    const long n0 = (long)blockIdx.x * 32;
    #pragma unroll
    for (int i = 0; i < 8; i++) {
        const int idx = t + i * 256;
        const int nl = idx >> 6, c4 = (idx & 63) * 4;
        *(float4*)&node_s[nl][c4] = *(const float4*)&node[(n0 + nl) * AH_ + c4];
    }
    __syncthreads();
    const int j0 = (t & 31) * 4;
    const int g  = t >> 5;
    float4 acc4[4];
    const float4 b = *(const float4*)&b_proj[j0];
    #pragma unroll
    for (int i = 0; i < 4; i++) acc4[i] = b;
    const float* wp = w_proj + j0;
    for (int c4 = 0; c4 < 64; c4++) {
        const float4 w0 = *(const float4*)&wp[(c4 * 4 + 0) * OUT_];
        const float4 w1 = *(const float4*)&wp[(c4 * 4 + 1) * OUT_];
        const float4 w2 = *(const float4*)&wp[(c4 * 4 + 2) * OUT_];
        const float4 w3 = *(const float4*)&wp[(c4 * 4 + 3) * OUT_];
        #pragma unroll
        for (int i = 0; i < 4; i++) {
            const float4 nv = *(const float4*)&node_s[g * 4 + i][c4 * 4];
            acc4[i].x += nv.x * w0.x + nv.y * w1.x + nv.z * w2.x + nv.w * w3.x;
            acc4[i].y += nv.x * w0.y + nv.y * w1.y + nv.z * w2.y + nv.w * w3.y;
            acc4[i].z += nv.x * w0.z + nv.y * w1.z + nv.z * w2.z + nv.w * w3.z;
            acc4[i].w += nv.x * w0.w + nv.y * w1.w + nv.z * w2.w + nv.w * w3.w;
        }
    }
    #pragma unroll
    for (int i = 0; i < 4; i++) {
        const long n = n0 + g * 4 + i;
        *(float4*)&out[n * OUT_ + j0] = acc4[i];
    }
}

extern "C" void kernel_launch(void* const* d_in, const int* in_sizes, int n_in,
                              void* d_out, int out_size, void* d_ws, size_t ws_size,
                              hipStream_t stream)
{
    const float* message      = (const float*)d_in[0];
    const float* edge_attr    = (const float*)d_in[1];
    const float* edge_scalars = (const float*)d_in[2];
    const float* w_rad1       = (const float*)d_in[3];
    const float* b_rad1       = (const float*)d_in[4];
    const float* w_rad2       = (const float*)d_in[5];
    const float* b_rad2       = (const float*)d_in[6];
    const float* w_dtp_v      = (const float*)d_in[7];
    const float* w_lin_act    = (const float*)d_in[8];
    const float* b_lin_act    = (const float*)d_in[9];
    const float* w_alpha      = (const float*)d_in[10];
    const float* b_alpha      = (const float*)d_in[11];
    const float* w_lin_v      = (const float*)d_in[12];
    const float* b_lin_v      = (const float*)d_in[13];
    const float* alpha_dot    = (const float*)d_in[14];
    const float* w_proj       = (const float*)d_in[15];
    const float* b_proj       = (const float*)d_in[16];
    const int*   edge_dst     = (const int*)d_in[17];

    const int E = in_sizes[0] / C_;
    const int N = out_size / OUT_;

    // ws layout (zeroed region first):
    // [node N*256 f32][amax N*8 u32][denom N*8 f32][deg N i32] |
    // [cursor N][sorted E][wpacks][msg_bf E*128 s][logits E*8 f32]
    char* ws = (char*)d_ws;
    float*    node     = (float*)ws;
    unsigned* amax_u   = (unsigned*)(node + (size_t)N * AH_);
    float*    denom    = (float*)(amax_u + (size_t)N * H_);
    int*      deg      = (int*)(denom + (size_t)N * H_);
    int*      cursor   = deg + N;
    int*      sorted   = cursor + N;
    short*    w_rad2_l = (short*)(sorted + E);
    short*    w_alph_l = w_rad2_l + 64 * 512;
    short*    w_lact_l = w_alph_l + 128 * 256;
    short*    w_linv_l = w_lact_l + 128 * 128;
    short*    msg_bf   = w_linv_l + 128 * 256;
    float*    logits   = (float*)(msg_bf + (size_t)E * C_);

    hipMemsetAsync(d_ws, 0, (size_t)N * (AH_ + 2 * H_ + 1) * 4, stream);

    const int nbE256 = (E + 255) / 256;
    k_pack_dtp<<<64, 64, 0, stream>>>(w_rad2, w_rad2_l);
    k_pack<<<(256/16)*(128/32), 64, 0, stream>>>(w_alpha,   w_alph_l, 128, 256);
    k_pack<<<(128/16)*(128/32), 64, 0, stream>>>(w_lin_act, w_lact_l, 128, 128);
    k_pack<<<(256/16)*(128/32), 64, 0, stream>>>(w_lin_v,   w_linv_l, 128, 256);
    k_hist<<<nbE256, 256, 0, stream>>>(edge_dst, deg, E);
    k_scan<<<1, 1024, 0, stream>>>(deg, cursor, N);
    k_fill<<<nbE256, 256, 0, stream>>>(edge_dst, cursor, sorted, E);
    k_msgalpha<<<E / 64, 512, 0, stream>>>(message, edge_attr, edge_scalars,
                                           w_rad1, b_rad1, w_rad2_l, b_rad2,
                                           w_alph_l, b_alpha, alpha_dot, edge_dst,
                                           msg_bf, logits, amax_u);
    k_denom<<<nbE256, 256, 0, stream>>>(logits, edge_dst, sorted, amax_u, denom, E);
    k_value<<<E / 32, 256, 0, stream>>>(msg_bf, edge_attr, w_lact_l, b_lin_act, w_dtp_v,
                                        w_linv_l, b_lin_v, logits, edge_dst, amax_u, denom,
                                        sorted, node);
    k_proj<<<N / 32, 256, 0, stream>>>(node, w_proj, b_proj, (float*)d_out);
}